// Round 1
// 195.499 us; speedup vs baseline: 1.0547x; 1.0547x over previous
//
#include <hip/hip_runtime.h>
#include <hip/hip_bf16.h>
#include <cstdint>

#define QLEN   1024
#define KLEN   2048
#define DMODEL 2048
#define BATCH  4
#define FLEN   (KLEN - QLEN + 1)   // 1025

typedef __bf16 bf16x8 __attribute__((ext_vector_type(8)));
typedef float  f32x4  __attribute__((ext_vector_type(4)));

// Static device scratch.
__device__ __align__(16) __bf16 g_ft[(size_t)QLEN * KLEN];           // FT, scale baked, bf16 (4 MB)
// Blocked y^T: g_yt[b][m/8][d][m%8]. Chunk (mt,d) = 8 consecutive m for one d
// = exactly one MFMA B-fragment slice. Producer writes it with NO transpose
// (contiguous 1 KB per wave); consumer global_load_lds-stages it chunk-major.
__device__ __align__(16) __bf16 g_yt[(size_t)BATCH * DMODEL * KLEN]; // 33.5 MB

typedef __attribute__((address_space(1))) void gvoid;
typedef __attribute__((address_space(3))) void svoid;

__device__ __forceinline__ void async_load16(const void* g, void* lds) {
  gvoid* gp = (gvoid*)(uintptr_t)g;
  svoid* sp = (svoid*)(uint32_t)(uintptr_t)lds;   // flat LDS addr low 32 bits == LDS offset
  __builtin_amdgcn_global_load_lds(gp, sp, 16, 0, 0);
}

// ---------------- prep: y^T (blocked) + FT generation, fused ----------------
// Round-4 theory: old gen_yt was structurally bound (62 us regardless of data
// source: VALUBusy 4%, occupancy 32%, dur identical for L3-hit vs HBM replays).
// The tile/barrier/transpose structure is deleted entirely: the blocked g_yt
// layout lets each wave stream 8 m x 64 d with coalesced 256 B reads and one
// contiguous 1 KB store. No LDS, no __syncthreads, no shuffles. FT generation
// (~2 us of VALU) rides along as trailing grid-stride units.
#define YT_UNITS (BATCH * (KLEN / 8) * (DMODEL / 64))  // 32768 wave-units
#define FT_UNITS ((QLEN * KLEN) / 512)                 // 4096 wave-units

__global__ __launch_bounds__(256) void prep_kernel(const float* __restrict__ x,
                                                   const float* __restrict__ p,
                                                   const int* __restrict__ addp) {
  const int lane  = threadIdx.x & 63;
  const int gw    = (blockIdx.x * 256 + threadIdx.x) >> 6;  // global wave id
  const int nw    = gridDim.x * 4;                          // total waves
  const int doadd = *addp;

  for (int u = gw; u < YT_UNITS + FT_UNITS; u += nw) {
    if (u < YT_UNITS) {
      // unit -> (b, mt, 64-wide d-block); lane owns one d column, 8 m rows.
      const int b  = u >> 13;          // 8192 units per batch (256 mt * 32 db)
      const int r5 = u & 8191;
      const int mt = r5 >> 5;
      const int db = r5 & 31;
      const int d  = db * 64 + lane;
      const float* xp = x + ((size_t)b * KLEN + mt * 8) * DMODEL + d;
      float v[8];
#pragma unroll
      for (int i = 0; i < 8; ++i) v[i] = xp[(size_t)i * DMODEL];  // 256 B/instr coalesced
      if (doadd) {
        const float* pp = p + ((size_t)b * KLEN + mt * 8) * DMODEL + d;
#pragma unroll
        for (int i = 0; i < 8; ++i) v[i] += pp[(size_t)i * DMODEL];
      }
      bf16x8 o;
#pragma unroll
      for (int i = 0; i < 8; ++i) o[i] = (__bf16)v[i];
      // wave writes 64 chunks * 16 B = contiguous 1 KB
      *(bf16x8*)(g_yt + ((size_t)b * (KLEN / 8) * DMODEL + (size_t)mt * DMODEL + d) * 8) = o;
    } else {
      // FT[l,m] = cos(2*pi*((l*(m-l)) % 1025)/1025)/sqrt(1025*2048) in band.
      const int uu = (u - YT_UNITS) * 64 + lane;   // [0, QLEN*KLEN/8)
      const int l  = uu >> 8;                      // KLEN/8 = 256 chunks per row
      const int m0 = (uu & 255) * 8;
      const int j0 = m0 - l;
      bf16x8 o = {};
      if (j0 + 7 >= 0 && j0 < FLEN) {
        const float w     = 6.283185307179586f / (float)FLEN;
        const float scale = 1.0f / sqrtf((float)FLEN * (float)KLEN);
#pragma unroll
        for (int i = 0; i < 8; ++i) {
          const int j = j0 + i;
          float vv = 0.0f;
          if (j >= 0 && j < FLEN) {
            const int rr = (l * j) % FLEN;         // exact: l*j < 2^20, magic-mul mod
            vv = cosf((float)rr * w) * scale;
          }
          o[i] = (__bf16)vv;
        }
      }
      *(bf16x8*)(g_ft + (size_t)uu * 8) = o;
    }
  }
}

// ---------------- GEMM: out[b][l][d] = sum_m FT[l][m] * y[m][d] ----------------
#define BM 128
#define BN 128
#define BK 64

__global__ __launch_bounds__(256) void gemm_kernel(float* __restrict__ out) {
  // grid: (DMODEL/BN, QLEN/BM, BATCH); 4 waves; wave tile 64x64 (4x4 of 16x16x32 MFMA)
  __shared__ __align__(16) __bf16 As[BM * BK];   // [l'][k'] chunk-swizzled, 16 KB
  __shared__ __align__(16) __bf16 Bs[BN * BK];   // chunk-major: chunk (c8, d') at idx c8*128+d', 16 KB
  const int bn = blockIdx.x, bm = blockIdx.y, b = blockIdx.z;
  const int l0 = bm * BM, d0 = bn * BN;
  const int tid  = threadIdx.x;
  const int lane = tid & 63;
  const int wave = tid >> 6;
  const int wr = wave >> 1, wc = wave & 1;
  const int col = lane & 15, quad = lane >> 4;

  f32x4 acc[4][4] = {};

  // band: FT[l,m] nonzero only for l <= m <= l+1024 -> K-tiles [l0/64, (l0+1151)/64]
  const int t0 = l0 >> 6;
  const int t1 = (l0 + BM - 1 + FLEN - 1) >> 6;   // inclusive; 18 tiles
  const __bf16* ftp = g_ft;
  const __bf16* ytp = g_yt + (size_t)b * DMODEL * KLEN;  // blocked [mt][d][8]

  for (int t = t0; t <= t1; ++t) {
    const int k0 = t * BK;
    // Stage A (FT): 128 rows x 64 k row-major, XOR swizzle on the GLOBAL side
    // (LDS linear; global_load_lds writes lane i at base + i*16).
#pragma unroll
    for (int s = 0; s < 4; ++s) {
      const int cb  = wave * 256 + s * 64;
      const int lc  = cb + lane;
      const int row = lc >> 3;
      const int gc8 = (lc & 7) ^ (row & 7);
      async_load16(ftp + (size_t)(l0 + row) * KLEN + k0 + gc8 * 8, As + cb * 8);
    }
    // Stage B (blocked y^T): chunk-major LDS, chunk (c, dd) <- g_yt[t*8+c][d0+dd].
    // Sweep lanes hit consecutive dd for fixed c -> contiguous 1 KB source reads.
    // Frag-read addr16 = c8*128 + r: residues r%8 cover all 8 bank groups -> no
    // swizzle needed (same distribution as the measured-0-conflict A path).
#pragma unroll
    for (int s = 0; s < 4; ++s) {
      const int idx = wave * 256 + s * 64 + lane;   // 0..1023
      const int c   = idx >> 7;                     // k-chunk 0..7
      const int dd  = idx & 127;
      async_load16(ytp + ((size_t)(t * 8 + c) * DMODEL + (d0 + dd)) * 8, Bs + (size_t)idx * 8);
    }
    __syncthreads();   // drains vmcnt -> staged data visible

#pragma unroll
    for (int kk = 0; kk < 2; ++kk) {
      bf16x8 af[4], bq[4];
      const int c8 = kk * 4 + quad;
#pragma unroll
      for (int ti = 0; ti < 4; ++ti) {
        const int r = wr * 64 + ti * 16 + col;            // A row (l), frag m = lane&15
        af[ti] = *(const bf16x8*)(As + (size_t)((r << 3) + (c8 ^ (r & 7))) * 8);
      }
#pragma unroll
      for (int tj = 0; tj < 4; ++tj) {
        const int r = wc * 64 + tj * 16 + col;            // B row (d), frag n = lane&15
        bq[tj] = *(const bf16x8*)(Bs + (size_t)((c8 << 7) + r) * 8);
      }
#pragma unroll
      for (int ti = 0; ti < 4; ++ti)
#pragma unroll
        for (int tj = 0; tj < 4; ++tj)
          acc[ti][tj] = __builtin_amdgcn_mfma_f32_16x16x32_bf16(af[ti], bq[tj], acc[ti][tj], 0, 0, 0);
    }
    __syncthreads();   // protect LDS from next iteration's staging
  }

  // Epilogue: C/D layout col = lane&15, row = quad*4 + reg  [m89/m91 verified]
#pragma unroll
  for (int ti = 0; ti < 4; ++ti) {
    const int l = l0 + wr * 64 + ti * 16 + quad * 4;
#pragma unroll
    for (int tj = 0; tj < 4; ++tj) {
      const int d = d0 + wc * 64 + tj * 16 + col;
      float* op = out + (size_t)b * QLEN * DMODEL + (size_t)l * DMODEL + d;
#pragma unroll
      for (int r2 = 0; r2 < 4; ++r2) op[(size_t)r2 * DMODEL] = acc[ti][tj][r2];
    }
  }
}

extern "C" void kernel_launch(void* const* d_in, const int* in_sizes, int n_in,
                              void* d_out, int out_size, void* d_ws, size_t ws_size,
                              hipStream_t stream) {
  const float* x   = (const float*)d_in[0];
  const float* p   = (const float*)d_in[1];
  const int* addp  = (const int*)d_in[3];   // add_position (qlen fixed at 1024 by shapes)
  float* out = (float*)d_out;

  prep_kernel<<<dim3(2048), dim3(256), 0, stream>>>(x, p, addp);
  gemm_kernel<<<dim3(DMODEL / BN, QLEN / BM, BATCH), dim3(256), 0, stream>>>(out);
}

// Round 3
// 188.694 us; speedup vs baseline: 1.0927x; 1.0361x over previous
//
#include <hip/hip_runtime.h>
#include <hip/hip_bf16.h>
#include <cstdint>

#define QLEN   1024
#define KLEN   2048
#define DMODEL 2048
#define BATCH  4
#define FLEN   (KLEN - QLEN + 1)   // 1025

typedef __bf16 bf16x8 __attribute__((ext_vector_type(8)));
typedef float  f32x4  __attribute__((ext_vector_type(4)));

// Static device scratch (FALLBACK ONLY — round-3 theory T_bss: module-BSS
// globals may live in poorly-interleaved/pessimal-MTYPE memory, capping write
// drain at ~0.6 TB/s, which would explain the structure-independent 63-us
// prep wall. Primary path: carve g_ft/g_yt from the harness d_ws workspace.)
__device__ __align__(16) __bf16 g_ft[(size_t)QLEN * KLEN];           // 4 MiB
__device__ __align__(16) __bf16 g_yt[(size_t)BATCH * DMODEL * KLEN]; // 32 MiB

typedef __attribute__((address_space(1))) void gvoid;
typedef __attribute__((address_space(3))) void svoid;

__device__ __forceinline__ void async_load16(const void* g, void* lds) {
  gvoid* gp = (gvoid*)(uintptr_t)g;
  svoid* sp = (svoid*)(uint32_t)(uintptr_t)lds;   // flat LDS addr low 32 bits == LDS offset
  __builtin_amdgcn_global_load_lds(gp, sp, 16, 0, 0);
}

// ---------------- prep: y^T (blocked) + FT generation, fused ----------------
// Body is byte-identical to the PASSING round-1 kernel (asm pin removed);
// the only change is that ft/yt destinations arrive as pointer params.
#define YT_UNITS (BATCH * (KLEN / 8) * (DMODEL / 64))  // 32768 wave-units
#define FT_UNITS ((QLEN * KLEN) / 512)                 // 4096 wave-units

__global__ __launch_bounds__(256) void prep_kernel(const float* __restrict__ x,
                                                   const float* __restrict__ p,
                                                   const int* __restrict__ addp,
                                                   __bf16* __restrict__ ftp,
                                                   __bf16* __restrict__ ytp) {
  __bf16* ft = ftp ? ftp : g_ft;
  __bf16* yt = ytp ? ytp : g_yt;
  const int lane  = threadIdx.x & 63;
  const int gw    = (blockIdx.x * 256 + threadIdx.x) >> 6;  // global wave id
  const int nw    = gridDim.x * 4;                          // total waves
  const int doadd = *addp;

  for (int u = gw; u < YT_UNITS + FT_UNITS; u += nw) {
    if (u < YT_UNITS) {
      // unit -> (b, mt, 64-wide d-block); lane owns one d column, 8 m rows.
      const int b  = u >> 13;          // 8192 units per batch (256 mt * 32 db)
      const int r5 = u & 8191;
      const int mt = r5 >> 5;
      const int db = r5 & 31;
      const int d  = db * 64 + lane;
      const float* xp = x + ((size_t)b * KLEN + mt * 8) * DMODEL + d;
      float v[8];
#pragma unroll
      for (int i = 0; i < 8; ++i) v[i] = xp[(size_t)i * DMODEL];  // 256 B/instr coalesced
      if (doadd) {
        const float* pp = p + ((size_t)b * KLEN + mt * 8) * DMODEL + d;
#pragma unroll
        for (int i = 0; i < 8; ++i) v[i] += pp[(size_t)i * DMODEL];
      }
      bf16x8 o;
#pragma unroll
      for (int i = 0; i < 8; ++i) o[i] = (__bf16)v[i];
      // wave writes 64 chunks * 16 B = contiguous 1 KB
      *(bf16x8*)(yt + ((size_t)b * (KLEN / 8) * DMODEL + (size_t)mt * DMODEL + d) * 8) = o;
    } else {
      // FT[l,m] = cos(2*pi*((l*(m-l)) % 1025)/1025)/sqrt(1025*2048) in band.
      const int uu = (u - YT_UNITS) * 64 + lane;   // [0, QLEN*KLEN/8)
      const int l  = uu >> 8;                      // KLEN/8 = 256 chunks per row
      const int m0 = (uu & 255) * 8;
      const int j0 = m0 - l;
      bf16x8 o = {};
      if (j0 + 7 >= 0 && j0 < FLEN) {
        const float w     = 6.283185307179586f / (float)FLEN;
        const float scale = 1.0f / sqrtf((float)FLEN * (float)KLEN);
#pragma unroll
        for (int i = 0; i < 8; ++i) {
          const int j = j0 + i;
          float vv = 0.0f;
          if (j >= 0 && j < FLEN) {
            const int rr = (l * j) % FLEN;         // exact: l*j < 2^20, magic-mul mod
            vv = cosf((float)rr * w) * scale;
          }
          o[i] = (__bf16)vv;
        }
      }
      *(bf16x8*)(ft + (size_t)uu * 8) = o;
    }
  }
}

// ---------------- GEMM: out[b][l][d] = sum_m FT[l][m] * y[m][d] ----------------
#define BM 128
#define BN 128
#define BK 64

__global__ __launch_bounds__(256) void gemm_kernel(float* __restrict__ out,
                                                   const __bf16* __restrict__ ftq,
                                                   const __bf16* __restrict__ ytq) {
  // grid: (DMODEL/BN, QLEN/BM, BATCH); 4 waves; wave tile 64x64 (4x4 of 16x16x32 MFMA)
  __shared__ __align__(16) __bf16 As[BM * BK];   // [l'][k'] chunk-swizzled, 16 KB
  __shared__ __align__(16) __bf16 Bs[BN * BK];   // chunk-major: chunk (c8, d') at idx c8*128+d', 16 KB
  const int bn = blockIdx.x, bm = blockIdx.y, b = blockIdx.z;
  const int l0 = bm * BM, d0 = bn * BN;
  const int tid  = threadIdx.x;
  const int lane = tid & 63;
  const int wave = tid >> 6;
  const int wr = wave >> 1, wc = wave & 1;
  const int col = lane & 15, quad = lane >> 4;

  f32x4 acc[4][4] = {};

  // band: FT[l,m] nonzero only for l <= m <= l+1024 -> K-tiles [l0/64, (l0+1151)/64]
  const int t0 = l0 >> 6;
  const int t1 = (l0 + BM - 1 + FLEN - 1) >> 6;   // inclusive; 18 tiles
  const __bf16* ftp = ftq ? ftq : g_ft;
  const __bf16* ytp = (ytq ? ytq : g_yt) + (size_t)b * DMODEL * KLEN;  // blocked [mt][d][8]

  for (int t = t0; t <= t1; ++t) {
    const int k0 = t * BK;
    // Stage A (FT): 128 rows x 64 k row-major, XOR swizzle on the GLOBAL side
    // (LDS linear; global_load_lds writes lane i at base + i*16).
#pragma unroll
    for (int s = 0; s < 4; ++s) {
      const int cb  = wave * 256 + s * 64;
      const int lc  = cb + lane;
      const int row = lc >> 3;
      const int gc8 = (lc & 7) ^ (row & 7);
      async_load16(ftp + (size_t)(l0 + row) * KLEN + k0 + gc8 * 8, As + cb * 8);
    }
    // Stage B (blocked y^T): chunk-major LDS, chunk (c, dd) <- yt[t*8+c][d0+dd].
    // Sweep lanes hit consecutive dd for fixed c -> contiguous 1 KB source reads.
    // Frag-read addr16 = c8*128 + r: residues r%8 cover all 8 bank groups -> no
    // swizzle needed (same distribution as the measured-0-conflict A path).
#pragma unroll
    for (int s = 0; s < 4; ++s) {
      const int idx = wave * 256 + s * 64 + lane;   // 0..1023
      const int c   = idx >> 7;                     // k-chunk 0..7
      const int dd  = idx & 127;
      async_load16(ytp + ((size_t)(t * 8 + c) * DMODEL + (d0 + dd)) * 8, Bs + (size_t)idx * 8);
    }
    __syncthreads();   // drains vmcnt -> staged data visible

#pragma unroll
    for (int kk = 0; kk < 2; ++kk) {
      bf16x8 af[4], bq[4];
      const int c8 = kk * 4 + quad;
#pragma unroll
      for (int ti = 0; ti < 4; ++ti) {
        const int r = wr * 64 + ti * 16 + col;            // A row (l), frag m = lane&15
        af[ti] = *(const bf16x8*)(As + (size_t)((r << 3) + (c8 ^ (r & 7))) * 8);
      }
#pragma unroll
      for (int tj = 0; tj < 4; ++tj) {
        const int r = wc * 64 + tj * 16 + col;            // B row (d), frag n = lane&15
        bq[tj] = *(const bf16x8*)(Bs + (size_t)((c8 << 7) + r) * 8);
      }
#pragma unroll
      for (int ti = 0; ti < 4; ++ti)
#pragma unroll
        for (int tj = 0; tj < 4; ++tj)
          acc[ti][tj] = __builtin_amdgcn_mfma_f32_16x16x32_bf16(af[ti], bq[tj], acc[ti][tj], 0, 0, 0);
    }
    __syncthreads();   // protect LDS from next iteration's staging
  }

  // Epilogue: C/D layout col = lane&15, row = quad*4 + reg  [m89/m91 verified]
#pragma unroll
  for (int ti = 0; ti < 4; ++ti) {
    const int l = l0 + wr * 64 + ti * 16 + quad * 4;
#pragma unroll
    for (int tj = 0; tj < 4; ++tj) {
      const int d = d0 + wc * 64 + tj * 16 + col;
      float* op = out + (size_t)b * QLEN * DMODEL + (size_t)l * DMODEL + d;
#pragma unroll
      for (int r2 = 0; r2 < 4; ++r2) op[(size_t)r2 * DMODEL] = acc[ti][tj][r2];
    }
  }
}

extern "C" void kernel_launch(void* const* d_in, const int* in_sizes, int n_in,
                              void* d_out, int out_size, void* d_ws, size_t ws_size,
                              hipStream_t stream) {
  const float* x   = (const float*)d_in[0];
  const float* p   = (const float*)d_in[1];
  const int* addp  = (const int*)d_in[3];   // add_position (qlen fixed at 1024 by shapes)
  float* out = (float*)d_out;

  // T_bss experiment: place ft/yt in the harness workspace (properly
  // interleaved hipMalloc memory) instead of module BSS. Both arrays are fully
  // rewritten every launch before any read, so ws re-poisoning is safe.
  const size_t FT_BYTES = (size_t)QLEN * KLEN * sizeof(__bf16);            // 4 MiB
  const size_t YT_BYTES = (size_t)BATCH * DMODEL * KLEN * sizeof(__bf16);  // 32 MiB
  __bf16* ft = nullptr;
  __bf16* yt = nullptr;
  char* ws = (char*)d_ws;
  if (ws && ws_size >= FT_BYTES + YT_BYTES) {
    ft = (__bf16*)ws;
    yt = (__bf16*)(ws + FT_BYTES);
  } else if (ws && ws_size >= YT_BYTES) {
    yt = (__bf16*)ws;           // prioritize the hot 32 MiB array
  }

  prep_kernel<<<dim3(2048), dim3(256), 0, stream>>>(x, p, addp, ft, yt);
  gemm_kernel<<<dim3(DMODEL / BN, QLEN / BM, BATCH), dim3(256), 0, stream>>>(out, ft, yt);
}